// Round 2
// baseline (120.991 us; speedup 1.0000x reference)
//
#include <hip/hip_runtime.h>

// Problem dims (fixed by reference setup_inputs)
#define B_  4
#define C_  3
#define S_  5
#define M_  18
#define HW  45056            // 256*176
#define HW4 (HW/4)           // 11264 float4s per plane/channel
#define G_  3                // planes (m) per block-group: X/Y loaded once per G planes
#define GPBS (M_/G_)         // 6 groups per (b,s)
#define NGROUP (B_*S_*GPBS)  // 120
#define SPLIT 11             // chunks per group
#define TPB 256
#define CHUNK4 (HW4/SPLIT)   // 1024 float4s per chunk
#define ITERS (CHUNK4/TPB)   // 4
#define NV (G_*16)           // 48 partial values per block
#define NPLANE (B_*S_*M_)    // 360

// Kernel A: per-(group,chunk) partial sums of 16 weighted moments for G_ planes.
// Value layout per plane j: [0]=msum, [1+c*5+{wx,wy,wxx,wyy,wxy}]
__global__ __launch_bounds__(TPB) void moments_kernel(
    const float4* __restrict__ X, const float4* __restrict__ Y,
    const float4* __restrict__ Mk, float* __restrict__ part) {
  int bid   = blockIdx.x;          // [0, NGROUP*SPLIT)
  int g     = bid / SPLIT;
  int chunk = bid - g * SPLIT;
  int bs    = g / GPBS;            // b*S_ + s
  int gm    = g - bs * GPBS;       // which group of G_ m-planes
  int b     = bs / S_;

  const float4* mp = Mk + (size_t)(bs * M_ + gm * G_) * HW4;
  const float4* xp = X  + (size_t)b * (C_ * HW4);
  const float4* yp = Y  + (size_t)b * (C_ * HW4);

  int base = chunk * CHUNK4 + (int)threadIdx.x;

  float acc[NV];
#pragma unroll
  for (int j = 0; j < NV; ++j) acc[j] = 0.f;

#pragma unroll
  for (int it = 0; it < ITERS; ++it) {
    int i = base + it * TPB;
    // issue all 12 loads up front for memory ILP
    float4 wv[G_], xv[C_], yv[C_];
#pragma unroll
    for (int j = 0; j < G_; ++j) wv[j] = mp[j * HW4 + i];
#pragma unroll
    for (int c = 0; c < C_; ++c) { xv[c] = xp[c * HW4 + i]; yv[c] = yp[c * HW4 + i]; }

    // rescale once, shared across the G_ planes
    float xs[C_][4], ys[C_][4];
#pragma unroll
    for (int c = 0; c < C_; ++c) {
      xs[c][0] = fmaf(xv[c].x, 0.5f, 0.5f); ys[c][0] = fmaf(yv[c].x, 0.5f, 0.5f);
      xs[c][1] = fmaf(xv[c].y, 0.5f, 0.5f); ys[c][1] = fmaf(yv[c].y, 0.5f, 0.5f);
      xs[c][2] = fmaf(xv[c].z, 0.5f, 0.5f); ys[c][2] = fmaf(yv[c].z, 0.5f, 0.5f);
      xs[c][3] = fmaf(xv[c].w, 0.5f, 0.5f); ys[c][3] = fmaf(yv[c].w, 0.5f, 0.5f);
    }

#pragma unroll
    for (int j = 0; j < G_; ++j) {
      float w4[4] = { wv[j].x, wv[j].y, wv[j].z, wv[j].w };
      float* a = acc + j * 16;
#pragma unroll
      for (int k = 0; k < 4; ++k) {
        float wk = w4[k];
        a[0] += wk;
#pragma unroll
        for (int c = 0; c < C_; ++c) {
          float xsv = xs[c][k], ysv = ys[c][k];
          float wx = wk * xsv, wy = wk * ysv;
          a[1 + c*5 + 0] = fmaf(wk, xsv, a[1 + c*5 + 0]);
          a[1 + c*5 + 1] = fmaf(wk, ysv, a[1 + c*5 + 1]);
          a[1 + c*5 + 2] = fmaf(wx, xsv, a[1 + c*5 + 2]);
          a[1 + c*5 + 3] = fmaf(wy, ysv, a[1 + c*5 + 3]);
          a[1 + c*5 + 4] = fmaf(wx, ysv, a[1 + c*5 + 4]);
        }
      }
    }
  }

  // wave-64 butterfly over all NV values
#pragma unroll
  for (int off = 32; off > 0; off >>= 1) {
#pragma unroll
    for (int j = 0; j < NV; ++j) acc[j] += __shfl_xor(acc[j], off);
  }

  __shared__ float red[TPB/64][NV];
  int lane = threadIdx.x & 63;
  int wv_  = threadIdx.x >> 6;
  if (lane == 0) {
#pragma unroll
    for (int j = 0; j < NV; ++j) red[wv_][j] = acc[j];
  }
  __syncthreads();
  if (threadIdx.x < NV) {
    float s = (red[0][threadIdx.x] + red[1][threadIdx.x]) +
              (red[2][threadIdx.x] + red[3][threadIdx.x]);
    part[(size_t)bid * NV + threadIdx.x] = s;
  }
}

// Kernel B: tiny epilogue. One block.
__global__ __launch_bounds__(384) void finalize_kernel(
    const float* __restrict__ part, float* __restrict__ out) {
  __shared__ float csS[NPLANE], ssS[NPLANE];
  __shared__ double csb[B_*S_], ssb[B_*S_];
  int t = threadIdx.x;

  if (t < NPLANE) {
    // plane t -> (bs, gm, j) -> group g, value base j*16
    int bs = t / M_;
    int m  = t - bs * M_;
    int gm = m / G_;
    int j  = m - gm * G_;
    int g  = bs * GPBS + gm;

    double s[16];
#pragma unroll
    for (int v = 0; v < 16; ++v) s[v] = 0.0;
    for (int ch = 0; ch < SPLIT; ++ch) {
      const float* p = part + (size_t)(g * SPLIT + ch) * NV + j * 16;
#pragma unroll
      for (int v = 0; v < 16; ++v) s[v] += (double)p[v];
    }

    const double C1d = 1e-4, C2d = 9e-4;
    double inv = 1.0 / (s[0] + 1e-6);
    double csAcc = 0.0, ssAcc = 0.0;
#pragma unroll
    for (int c = 0; c < C_; ++c) {
      double mu1  = s[1 + c*5 + 0] * inv;
      double mu2  = s[1 + c*5 + 1] * inv;
      double mu11 = s[1 + c*5 + 2] * inv;
      double mu22 = s[1 + c*5 + 3] * inv;
      double mu12 = s[1 + c*5 + 4] * inv;
      double m1s = mu1*mu1, m2s = mu2*mu2, m12 = mu1*mu2;
      double sig1  = mu11 - m1s;
      double sig2  = mu22 - m2s;
      double sig12 = mu12 - m12;
      double cs   = (2.0*sig12 + C2d) / (sig1 + sig2 + C2d);
      double ssim = (2.0*m12 + C1d) / (m1s + m2s + C1d) * cs;
      if (cs   < 0.0) cs   = 0.0;
      if (ssim < 0.0) ssim = 0.0;
      csAcc += cs; ssAcc += ssim;
    }
    csS[t] = (float)csAcc;
    ssS[t] = (float)ssAcc;
  }
  __syncthreads();

  if (t < B_*S_) {  // t = b*S_ + s
    double cb = 0.0, sb = 0.0;
    for (int m = 0; m < M_; ++m) { cb += (double)csS[t*M_ + m]; sb += (double)ssS[t*M_ + m]; }
    csb[t] = cb / (double)(M_*C_);
    ssb[t] = sb / (double)(M_*C_);
  }
  __syncthreads();

  if (t == 0) {
    double acc = 0.0;
    for (int b = 0; b < B_; ++b) {
      double p = ssb[b*S_ + (S_-1)];
      for (int s = 0; s < S_-1; ++s) p *= csb[b*S_ + s];
      acc += p;
    }
    out[0] = (float)(acc / (double)B_);
  }
}

extern "C" void kernel_launch(void* const* d_in, const int* in_sizes, int n_in,
                              void* d_out, int out_size, void* d_ws, size_t ws_size,
                              hipStream_t stream) {
  (void)in_sizes; (void)n_in; (void)out_size; (void)ws_size;
  const float4* X  = (const float4*)d_in[0];
  const float4* Y  = (const float4*)d_in[1];
  const float4* Mk = (const float4*)d_in[2];
  float* part = (float*)d_ws;        // NGROUP*SPLIT*NV floats = 253 KB
  float* out  = (float*)d_out;

  hipLaunchKernelGGL(moments_kernel, dim3(NGROUP*SPLIT), dim3(TPB), 0, stream,
                     X, Y, Mk, part);
  hipLaunchKernelGGL(finalize_kernel, dim3(1), dim3(384), 0, stream, part, out);
}